// Round 1
// baseline (3311.405 us; speedup 1.0000x reference)
//
#include <hip/hip_runtime.h>
#include <hip/hip_bf16.h>
#include <math.h>
#include <stdint.h>

#define BDIM 512
#define NN 128
#define NF 133
#define OH 60      // NHID
#define NH 8       // NHEADS
#define HIDD 300
#define HCAT 480   // NH*OH
#define FPD 1489
#define FP2D 512
#define LRA 0.2f

typedef __hip_bfloat16 bf16;

__device__ __forceinline__ float ldw(const float* p){ return *p; }
__device__ __forceinline__ float ldw(const bf16* p){ return __bfloat162float(*p); }
__device__ __forceinline__ void stw(float* p, float v){ *p = v; }
__device__ __forceinline__ void stw(bf16* p, float v){ *p = __float2bfloat16(v); }

__device__ __forceinline__ float warp_max(float v){
  #pragma unroll
  for (int s = 32; s; s >>= 1) v = fmaxf(v, __shfl_xor(v, s));
  return v;
}
__device__ __forceinline__ float warp_sum(float v){
  #pragma unroll
  for (int s = 32; s; s >>= 1) v += __shfl_xor(v, s);
  return v;
}

// ---------------- GAT layer 1: per (batch, head) ----------------
// Wh = x_b @ W_heads[h]  (128x133 @ 133x60, LDS-resident)
// s,d = Wh . a_src/a_dst ; e_ij = lrelu(s_i+d_j) masked; softmax; hp = att@Wh; elu -> h
template<typename TH>
__global__ __launch_bounds__(256) void k_gat1(
    const float* __restrict__ x, const int* __restrict__ adj,
    const float* __restrict__ Whw, const float* __restrict__ asrc,
    const float* __restrict__ adst, TH* __restrict__ hbuf)
{
  __shared__ float Whl[NN][61];                 // pad 61: conflict-free row reads
  __shared__ unsigned long long mA[NN], mB[NN]; // adjacency bitmasks
  __shared__ float sarr[NN], darr[NN];
  __shared__ float attrow[4][NN];

  const int t = threadIdx.x, lane = t & 63, w = t >> 6;
  const int b = blockIdx.x >> 3, hd = blockIdx.x & 7;
  const float* xb = x + (size_t)b * NN * NF;
  const int* adjb = adj + (size_t)b * NN * NN;
  const float* Wg = Whw + (size_t)hd * NF * OH;

  // adjacency bitmasks: wave w owns rows [w*32, w*32+32)
  for (int i = w * 32; i < w * 32 + 32; ++i) {
    unsigned long long b0 = __ballot(adjb[i * NN + lane] > 0);
    unsigned long long b1 = __ballot(adjb[i * NN + 64 + lane] > 0);
    if (lane == 0) { mA[i] = b0; mB[i] = b1; }
  }

  // Wh GEMM: threads t<240: col j = t%60, row-group rg = t/60 (32 rows each)
  if (t < 240) {
    const int j = t % 60, rg = t / 60;
    for (int ii = 0; ii < 32; ++ii) {
      const int i = rg * 32 + ii;
      const float* xr = xb + i * NF;
      float acc = 0.f;
      #pragma unroll 7
      for (int k = 0; k < NF; ++k) acc += xr[k] * Wg[k * OH + j];
      Whl[i][j] = acc;
    }
  }
  __syncthreads();

  // s, d (one thread per row)
  if (t < NN) {
    float s_ = 0.f, d_ = 0.f;
    #pragma unroll
    for (int j = 0; j < OH; ++j) {
      float wv = Whl[t][j];
      s_ += wv * asrc[hd * OH + j];
      d_ += wv * adst[hd * OH + j];
    }
    sarr[t] = s_; darr[t] = d_;
  }
  __syncthreads();

  // attention + PV, wave-parallel per row
  const int cl = lane < OH ? lane : OH - 1;
  for (int i = w * 32; i < w * 32 + 32; ++i) {
    const unsigned long long ma = mA[i], mb = mB[i];
    const float si = sarr[i];
    float e1 = -3e38f, e2 = -3e38f;
    if ((ma >> lane) & 1ull) { float v = si + darr[lane];      e1 = v > 0.f ? v : LRA * v; }
    if ((mb >> lane) & 1ull) { float v = si + darr[64 + lane]; e2 = v > 0.f ? v : LRA * v; }
    float m = warp_max(fmaxf(e1, e2));
    float p1 = ((ma >> lane) & 1ull) ? __expf(e1 - m) : 0.f;  // masked -> exact 0
    float p2 = ((mb >> lane) & 1ull) ? __expf(e2 - m) : 0.f;
    float inv = 1.f / warp_sum(p1 + p2);
    attrow[w][lane] = p1 * inv;
    attrow[w][64 + lane] = p2 * inv;
    float acc = 0.f;
    #pragma unroll 8
    for (int j = 0; j < NN; ++j) acc += attrow[w][j] * Whl[j][cl];
    if (lane < OH) {
      float o = acc > 0.f ? acc : __expf(acc) - 1.f;   // ELU
      stw(&hbuf[((size_t)(b * NN + i)) * HCAT + hd * OH + lane], o);
    }
  }
}

// ---------------- Wo = h_b @ W_out  (128x480 @ 480x300) ----------------
template<typename TH, typename TW>
__global__ __launch_bounds__(512) void k_wo(
    const TH* __restrict__ hbuf, const float* __restrict__ Wout, TW* __restrict__ Wo)
{
  __shared__ float ht[NN][36];     // k-tile 32, padded (16B-aligned rows)
  __shared__ float wt[32][304];    // col-padded so q*76 starts are 16B-aligned
  const int t = threadIdx.x;
  const int b = blockIdx.x;
  const int i = t >> 2, q = t & 3;  // row, col-quarter (76 cols, last 4 dummy)
  float acc[76];
  #pragma unroll
  for (int c = 0; c < 76; ++c) acc[c] = 0.f;

  for (int kt = 0; kt < HCAT; kt += 32) {
    for (int idx = t; idx < NN * 32; idx += 512) {
      int r = idx >> 5, k = idx & 31;
      ht[r][k] = ldw(&hbuf[((size_t)(b * NN + r)) * HCAT + kt + k]);
    }
    for (int idx = t; idx < 32 * 304; idx += 512) {
      int r = idx / 304, c = idx - r * 304;
      wt[r][c] = (c < HIDD) ? Wout[(size_t)(kt + r) * HIDD + c] : 0.f;
    }
    __syncthreads();
    #pragma unroll 4
    for (int k = 0; k < 32; ++k) {
      float a = ht[i][k];
      const float* wr = &wt[k][q * 76];
      #pragma unroll
      for (int c = 0; c < 76; ++c) acc[c] += a * wr[c];
    }
    __syncthreads();
  }
  #pragma unroll
  for (int c = 0; c < 76; ++c) {
    int cc = q * 76 + c;
    if (cc < HIDD) stw(&Wo[((size_t)(b * NN + i)) * HIDD + cc], acc[c]);
  }
}

// ---------------- GAT layer 2 + log_softmax + mean (rank-1 trick) ----------------
template<typename TW>
__global__ __launch_bounds__(256) void k_gat2(
    const TW* __restrict__ Wo, const int* __restrict__ adj,
    const float* __restrict__ aos, const float* __restrict__ aod,
    float* __restrict__ gat)
{
  __shared__ unsigned long long mA[NN], mB[NN];
  __shared__ float so[NN], dof[NN];
  __shared__ bf16 att[NN][136];        // transposed att[j][i], 16B-aligned rows
  __shared__ float aosl[HIDD], aodl[HIDD];
  __shared__ float colsum[HIDD + 4];
  __shared__ float svals[4];

  const int t = threadIdx.x, lane = t & 63, w = t >> 6;
  const int b = blockIdx.x;
  const int* adjb = adj + (size_t)b * NN * NN;
  const TW* wob = Wo + (size_t)b * NN * HIDD;

  for (int c = t; c < HIDD; c += 256) { aosl[c] = aos[c]; aodl[c] = aod[c]; }
  for (int c = t; c < HIDD + 4; c += 256) colsum[c] = 0.f;

  // masks + so/do (wave per row)
  for (int i = w * 32; i < w * 32 + 32; ++i) {
    unsigned long long b0 = __ballot(adjb[i * NN + lane] > 0);
    unsigned long long b1 = __ballot(adjb[i * NN + 64 + lane] > 0);
    if (lane == 0) { mA[i] = b0; mB[i] = b1; }
    float s_ = 0.f, d_ = 0.f;
    for (int c = lane; c < HIDD; c += 64) {
      float wv = ldw(&wob[(size_t)i * HIDD + c]);
      s_ += wv * aosl[c];
      d_ += wv * aodl[c];
    }
    s_ = warp_sum(s_); d_ = warp_sum(d_);
    if (lane == 0) { so[i] = s_; dof[i] = d_; }
  }
  __syncthreads();

  // attention rows -> transposed bf16 att
  for (int i = w * 32; i < w * 32 + 32; ++i) {
    const unsigned long long ma = mA[i], mb = mB[i];
    const float si = so[i];
    float e1 = -3e38f, e2 = -3e38f;
    if ((ma >> lane) & 1ull) { float v = si + dof[lane];      e1 = v > 0.f ? v : LRA * v; }
    if ((mb >> lane) & 1ull) { float v = si + dof[64 + lane]; e2 = v > 0.f ? v : LRA * v; }
    float m = warp_max(fmaxf(e1, e2));
    float p1 = ((ma >> lane) & 1ull) ? __expf(e1 - m) : 0.f;
    float p2 = ((mb >> lane) & 1ull) ? __expf(e2 - m) : 0.f;
    float inv = 1.f / warp_sum(p1 + p2);
    att[lane][i] = __float2bfloat16(p1 * inv);
    att[64 + lane][i] = __float2bfloat16(p2 * inv);
  }
  __syncthreads();

  // PV: group w owns rows [w*32, w*32+32), cols tiled by 64 lanes.
  // ho never materialized: gat[c] = colsum[c]/128 - (sum_i m_i+lse_i)/128
  float mrow[32], lrow[32];
  #pragma unroll
  for (int r = 0; r < 32; ++r) { mrow[r] = -3e38f; lrow[r] = 0.f; }

  for (int ct = 0; ct < 5; ++ct) {
    const int c = ct * 64 + lane;
    const bool cv = c < HIDD;
    float acc[32];
    #pragma unroll
    for (int r = 0; r < 32; ++r) acc[r] = 0.f;
    for (int j = 0; j < NN; ++j) {
      float wv = cv ? ldw(&wob[(size_t)j * HIDD + c]) : 0.f;
      const uint32_t* ar = reinterpret_cast<const uint32_t*>(&att[j][w * 32]);
      #pragma unroll
      for (int rr = 0; rr < 16; ++rr) {
        uint32_t pk = ar[rr];
        float a0 = __uint_as_float(pk << 16);
        float a1 = __uint_as_float(pk & 0xffff0000u);
        acc[2 * rr]     += a0 * wv;
        acc[2 * rr + 1] += a1 * wv;
      }
    }
    float csum = 0.f;
    #pragma unroll
    for (int r = 0; r < 32; ++r) {
      float v = acc[r] > 0.f ? acc[r] : __expf(acc[r]) - 1.f;  // ELU
      float vv = cv ? v : -3e38f;
      float tm = warp_max(vv);
      float nm = fmaxf(mrow[r], tm);
      float pe = cv ? __expf(vv - nm) : 0.f;
      float ts = warp_sum(pe);
      lrow[r] = lrow[r] * __expf(mrow[r] - nm) + ts;
      mrow[r] = nm;
      if (cv) csum += v;
    }
    if (cv) atomicAdd(&colsum[c], csum);
  }
  if (lane == 0) {
    float ssum = 0.f;
    #pragma unroll
    for (int r = 0; r < 32; ++r) ssum += mrow[r] + __logf(lrow[r]);
    svals[w] = ssum;
  }
  __syncthreads();
  const float S = svals[0] + svals[1] + svals[2] + svals[3];
  for (int c = t; c < HIDD; c += 256)
    gat[(size_t)b * HIDD + c] = (colsum[c] - S) * (1.f / 128.f);
}

// ---------------- FPN branch ----------------
__global__ __launch_bounds__(256) void k_fpn(
    const float* __restrict__ fp, const float* __restrict__ w1, const float* __restrict__ b1,
    const float* __restrict__ w2, const float* __restrict__ b2, float* __restrict__ fpn)
{
  __shared__ float f1[FP2D];
  const int t = threadIdx.x, b = blockIdx.x;
  const float* fpr = fp + (size_t)b * FPD;
  for (int c = t; c < FP2D; c += 256) {
    float acc = b1[c];
    #pragma unroll 4
    for (int k = 0; k < FPD; ++k) acc += fpr[k] * w1[(size_t)k * FP2D + c];
    f1[c] = fmaxf(acc, 0.f);
  }
  __syncthreads();
  for (int c = t; c < HIDD; c += 256) {
    float acc = b2[c];
    #pragma unroll 4
    for (int k = 0; k < FP2D; ++k) acc += f1[k] * w2[(size_t)k * HIDD + c];
    fpn[(size_t)b * HIDD + c] = acc;
  }
}

// ---------------- fusion head ----------------
__global__ __launch_bounds__(256) void k_head(
    const float* __restrict__ gat, const float* __restrict__ fpn,
    const float* __restrict__ gw, const float* __restrict__ gb,
    const float* __restrict__ fw, const float* __restrict__ fb,
    const float* __restrict__ w1, const float* __restrict__ b1,
    const float* __restrict__ w2, const float* __restrict__ b2,
    float* __restrict__ out)
{
  __shared__ float zl[2 * HIDD];
  __shared__ float z1l[HIDD];
  __shared__ float red[4];
  const int t = threadIdx.x, b = blockIdx.x, lane = t & 63, w = t >> 6;
  const float* gr = gat + (size_t)b * HIDD;
  const float* fr = fpn + (size_t)b * HIDD;
  for (int c = t; c < HIDD; c += 256) {
    float ag = gb[c], af = fb[c];
    for (int k = 0; k < HIDD; ++k) {
      ag += gr[k] * gw[(size_t)k * HIDD + c];
      af += fr[k] * fw[(size_t)k * HIDD + c];
    }
    zl[c] = fmaxf(ag, 0.f);
    zl[HIDD + c] = fmaxf(af, 0.f);
  }
  __syncthreads();
  for (int c = t; c < HIDD; c += 256) {
    float acc = b1[c];
    for (int k = 0; k < 2 * HIDD; ++k) acc += zl[k] * w1[(size_t)k * HIDD + c];
    z1l[c] = fmaxf(acc, 0.f);
  }
  __syncthreads();
  float p = 0.f;
  for (int k = t; k < HIDD; k += 256) p += z1l[k] * w2[k];
  p = warp_sum(p);
  if (lane == 0) red[w] = p;
  __syncthreads();
  if (t == 0) {
    float z = red[0] + red[1] + red[2] + red[3] + b2[0];
    out[b] = 1.f / (1.f + __expf(-z));   // sigmoid (TASK=1)
  }
}

extern "C" void kernel_launch(void* const* d_in, const int* in_sizes, int n_in,
                              void* d_out, int out_size, void* d_ws, size_t ws_size,
                              hipStream_t stream)
{
  const float* x    = (const float*)d_in[0];
  const int*   adj  = (const int*)d_in[1];
  const float* fp   = (const float*)d_in[2];
  const float* Whw  = (const float*)d_in[3];
  const float* asrc = (const float*)d_in[4];
  const float* adst = (const float*)d_in[5];
  const float* Wout = (const float*)d_in[6];
  const float* aos  = (const float*)d_in[7];
  const float* aod  = (const float*)d_in[8];
  const float* fc1w = (const float*)d_in[9];
  const float* fc1b = (const float*)d_in[10];
  const float* fc2w = (const float*)d_in[11];
  const float* fc2b = (const float*)d_in[12];
  const float* fcgw = (const float*)d_in[13];
  const float* fcgb = (const float*)d_in[14];
  const float* fcfw = (const float*)d_in[15];
  const float* fcfb = (const float*)d_in[16];
  const float* f1w  = (const float*)d_in[17];
  const float* f1b  = (const float*)d_in[18];
  const float* f2w  = (const float*)d_in[19];
  const float* f2b  = (const float*)d_in[20];
  float* out = (float*)d_out;

  const size_t nH  = (size_t)BDIM * NN * HCAT;   // 31,457,280
  const size_t nWo = (size_t)BDIM * NN * HIDD;   // 19,660,800
  const size_t nG  = (size_t)BDIM * HIDD;        // 153,600

  char* wsb = (char*)d_ws;
  const size_t need32 = (nH + nWo + 2 * nG) * 4;   // ~206 MB

  if (ws_size >= need32) {
    float* h    = (float*)wsb;
    float* Wo   = (float*)(wsb + nH * 4);
    float* gatp = (float*)(wsb + (nH + nWo) * 4);
    float* fpnp = gatp + nG;
    k_gat1<float><<<BDIM * NH, 256, 0, stream>>>(x, adj, Whw, asrc, adst, h);
    k_wo<float, float><<<BDIM, 512, 0, stream>>>(h, Wout, Wo);
    k_gat2<float><<<BDIM, 256, 0, stream>>>(Wo, adj, aos, aod, gatp);
    k_fpn<<<BDIM, 256, 0, stream>>>(fp, fc1w, fc1b, fc2w, fc2b, fpnp);
    k_head<<<BDIM, 256, 0, stream>>>(gatp, fpnp, fcgw, fcgb, fcfw, fcfb,
                                     f1w, f1b, f2w, f2b, out);
  } else {
    // bf16-storage fallback (~104 MB scratch); error ~0.3% << 2% threshold
    bf16* h    = (bf16*)wsb;
    bf16* Wo   = (bf16*)(wsb + nH * 2);
    float* gatp = (float*)(wsb + (nH + nWo) * 2);
    float* fpnp = gatp + nG;
    k_gat1<bf16><<<BDIM * NH, 256, 0, stream>>>(x, adj, Whw, asrc, adst, h);
    k_wo<bf16, bf16><<<BDIM, 512, 0, stream>>>(h, Wout, Wo);
    k_gat2<bf16><<<BDIM, 256, 0, stream>>>(Wo, adj, aos, aod, gatp);
    k_fpn<<<BDIM, 256, 0, stream>>>(fp, fc1w, fc1b, fc2w, fc2b, fpnp);
    k_head<<<BDIM, 256, 0, stream>>>(gatp, fpnp, fcgw, fcgb, fcfw, fcfb,
                                     f1w, f1b, f2w, f2b, out);
  }
}

// Round 2
// 1207.446 us; speedup vs baseline: 2.7425x; 2.7425x over previous
//
#include <hip/hip_runtime.h>
#include <hip/hip_bf16.h>
#include <math.h>
#include <stdint.h>

#define NN 128
#define LRA 0.2f

typedef __attribute__((ext_vector_type(8))) short bf16x8;
typedef __attribute__((ext_vector_type(4))) float f32x4;

__device__ __forceinline__ unsigned short f2bf(float v) {
  union { float f; unsigned int u; } a; a.f = v;
  unsigned int u = a.u;
  return (unsigned short)((u + 0x7fffu + ((u >> 16) & 1u)) >> 16);
}
__device__ __forceinline__ float bf2f(unsigned short h) {
  union { float f; unsigned int u; } a; a.u = ((unsigned int)h) << 16;
  return a.f;
}

__device__ __forceinline__ float warp_max(float v){
  #pragma unroll
  for (int s = 32; s; s >>= 1) v = fmaxf(v, __shfl_xor(v, s));
  return v;
}
__device__ __forceinline__ float warp_sum(float v){
  #pragma unroll
  for (int s = 32; s; s >>= 1) v += __shfl_xor(v, s);
  return v;
}

// ================= generic split-bf16 MFMA GEMM =================
// C[M,N] = A[M,K] @ B[K,N], f32 in/out, 3-term hi/lo split (err ~2^-17).
// MODE 0: B row-major [K][N]. MODE 1: B = Bcat from W_heads[8][133][60],
//   Bcat[k][h*60+j] = W_heads[h][k][j].
template<int BN, int MODE, bool AL4>
__global__ __launch_bounds__(256) void k_gemm(
    const float* __restrict__ A, const float* __restrict__ B,
    float* __restrict__ C, int M, int K, int N)
{
  constexpr int NT = BN / 16;
  __shared__ unsigned short Ah[128][40], Al[128][40];
  __shared__ unsigned short Bh[BN][40],  Bl[BN][40];
  const int t = threadIdx.x, lane = t & 63, w = t >> 6;
  const int r = lane & 15, g = lane >> 4;
  const int row0 = blockIdx.x * 128, col0 = blockIdx.y * BN;

  f32x4 acc[2][NT];
  #pragma unroll
  for (int mt = 0; mt < 2; ++mt)
    #pragma unroll
    for (int nt = 0; nt < NT; ++nt) acc[mt][nt] = (f32x4){0.f, 0.f, 0.f, 0.f};

  for (int kt = 0; kt < K; kt += 32) {
    // ---- stage A tile 128x32 (f32 -> hi/lo bf16) ----
    #pragma unroll
    for (int ii = 0; ii < 4; ++ii) {
      const int i = t + ii * 256;
      const int ar = i >> 3, aq = (i & 7) * 4;
      const int gk = kt + aq;
      const float* ap = &A[(size_t)(row0 + ar) * K + gk];
      float v0 = 0.f, v1 = 0.f, v2 = 0.f, v3 = 0.f;
      if (AL4 && gk + 3 < K) {
        float4 v = *(const float4*)ap; v0 = v.x; v1 = v.y; v2 = v.z; v3 = v.w;
      } else {
        if (gk     < K) v0 = ap[0];
        if (gk + 1 < K) v1 = ap[1];
        if (gk + 2 < K) v2 = ap[2];
        if (gk + 3 < K) v3 = ap[3];
      }
      unsigned short h0 = f2bf(v0), h1 = f2bf(v1), h2 = f2bf(v2), h3 = f2bf(v3);
      Ah[ar][aq] = h0; Ah[ar][aq+1] = h1; Ah[ar][aq+2] = h2; Ah[ar][aq+3] = h3;
      Al[ar][aq]   = f2bf(v0 - bf2f(h0));
      Al[ar][aq+1] = f2bf(v1 - bf2f(h1));
      Al[ar][aq+2] = f2bf(v2 - bf2f(h2));
      Al[ar][aq+3] = f2bf(v3 - bf2f(h3));
    }
    // ---- stage B tile 32xBN transposed -> Bt[n][k] ----
    #pragma unroll
    for (int ii = 0; ii < NT; ++ii) {
      const int i = t + ii * 256;
      const int n = i % BN, kk = (i / BN) * 2;
      const int gn = col0 + n;
      float v0 = 0.f, v1 = 0.f;
      if (MODE == 0) {
        if (gn < N) {
          if (kt + kk     < K) v0 = B[(size_t)(kt + kk) * N + gn];
          if (kt + kk + 1 < K) v1 = B[(size_t)(kt + kk + 1) * N + gn];
        }
      } else {
        if (gn < N) {
          const int hh = gn / 60, jj = gn - hh * 60;
          if (kt + kk     < K) v0 = B[((size_t)hh * 133 + (kt + kk)) * 60 + jj];
          if (kt + kk + 1 < K) v1 = B[((size_t)hh * 133 + (kt + kk + 1)) * 60 + jj];
        }
      }
      unsigned short h0 = f2bf(v0), h1 = f2bf(v1);
      Bh[n][kk] = h0; Bh[n][kk+1] = h1;
      Bl[n][kk]   = f2bf(v0 - bf2f(h0));
      Bl[n][kk+1] = f2bf(v1 - bf2f(h1));
    }
    __syncthreads();
    // ---- compute ----
    bf16x8 ah[2], al[2];
    #pragma unroll
    for (int mt = 0; mt < 2; ++mt) {
      const int rr = w * 32 + mt * 16 + r;
      ah[mt] = *(const bf16x8*)&Ah[rr][g * 8];
      al[mt] = *(const bf16x8*)&Al[rr][g * 8];
    }
    #pragma unroll
    for (int nt = 0; nt < NT; ++nt) {
      const bf16x8 bh = *(const bf16x8*)&Bh[nt * 16 + r][g * 8];
      const bf16x8 bl = *(const bf16x8*)&Bl[nt * 16 + r][g * 8];
      #pragma unroll
      for (int mt = 0; mt < 2; ++mt) {
        acc[mt][nt] = __builtin_amdgcn_mfma_f32_16x16x32_bf16(ah[mt], bh, acc[mt][nt], 0, 0, 0);
        acc[mt][nt] = __builtin_amdgcn_mfma_f32_16x16x32_bf16(al[mt], bh, acc[mt][nt], 0, 0, 0);
        acc[mt][nt] = __builtin_amdgcn_mfma_f32_16x16x32_bf16(ah[mt], bl, acc[mt][nt], 0, 0, 0);
      }
    }
    __syncthreads();
  }
  // ---- store (C/D: col = lane&15, row = 4*(lane>>4)+reg  [m89]) ----
  #pragma unroll
  for (int mt = 0; mt < 2; ++mt)
    #pragma unroll
    for (int nt = 0; nt < NT; ++nt) {
      const int cc = col0 + nt * 16 + r;
      if (cc < N) {
        #pragma unroll
        for (int q = 0; q < 4; ++q) {
          const int rr = row0 + w * 32 + mt * 16 + g * 4 + q;
          C[(size_t)rr * N + cc] = acc[mt][nt][q];
        }
      }
    }
}

// ================= GAT layer 1 attention (per batch, loops 8 heads) =========
// Reads Wh[b*128..][480] (f32), writes h = elu(att@Wh) IN-PLACE (same cols).
__global__ __launch_bounds__(512) void k_att1(
    float* __restrict__ Wh, const int* __restrict__ adj,
    const float* __restrict__ asrc, const float* __restrict__ adst)
{
  __shared__ unsigned short Th[64][136], Tl[64][136];   // WhT hi/lo  [col][node]
  __shared__ float att[128][132];
  __shared__ unsigned long long mA[128], mB[128];
  __shared__ float sarr[128], darr[128];
  __shared__ float asl[64], adl[64];

  const int t = threadIdx.x, lane = t & 63, w = t >> 6;
  const int r = lane & 15, g = lane >> 4;
  const int b = blockIdx.x;
  const int* adjb = adj + (size_t)b * NN * NN;
  float* whb = Wh + (size_t)b * NN * 480;

  // adjacency masks once
  #pragma unroll 4
  for (int rr2 = 0; rr2 < 16; ++rr2) {
    const int i = w * 16 + rr2;
    unsigned long long b0 = __ballot(adjb[i * NN + lane] > 0);
    unsigned long long b1 = __ballot(adjb[i * NN + 64 + lane] > 0);
    if (lane == 0) { mA[i] = b0; mB[i] = b1; }
  }
  __syncthreads();

  for (int hd = 0; hd < 8; ++hd) {
    if (t < 64) {
      asl[t] = (t < 60) ? asrc[hd * 60 + t] : 0.f;
      adl[t] = (t < 60) ? adst[hd * 60 + t] : 0.f;
    }
    // stage WhT hi/lo (wave w reads row j = jb*8+w, lanes = cols)
    for (int jb = 0; jb < 16; ++jb) {
      const int j = jb * 8 + (t >> 6);
      const int c = t & 63;
      float v = (c < 60) ? whb[(size_t)j * 480 + hd * 60 + c] : 0.f;
      unsigned short h = f2bf(v);
      Th[c][j] = h; Tl[c][j] = f2bf(v - bf2f(h));
    }
    __syncthreads();
    // s, d per node
    if (t < 128) {
      float s_ = 0.f, d_ = 0.f;
      #pragma unroll 4
      for (int c = 0; c < 60; ++c) {
        float wv = bf2f(Th[c][t]) + bf2f(Tl[c][t]);
        s_ += wv * asl[c]; d_ += wv * adl[c];
      }
      sarr[t] = s_; darr[t] = d_;
    }
    __syncthreads();
    // softmax rows (wave w: rows w*16..w*16+15)
    for (int rr2 = 0; rr2 < 16; ++rr2) {
      const int i = w * 16 + rr2;
      const unsigned long long ma = mA[i], mb2 = mB[i];
      const float si = sarr[i];
      float e1 = -3e38f, e2 = -3e38f;
      if ((ma  >> lane) & 1ull) { float v = si + darr[lane];      e1 = v > 0.f ? v : LRA * v; }
      if ((mb2 >> lane) & 1ull) { float v = si + darr[64 + lane]; e2 = v > 0.f ? v : LRA * v; }
      float m = warp_max(fmaxf(e1, e2));
      float p1 = ((ma  >> lane) & 1ull) ? __expf(e1 - m) : 0.f;
      float p2 = ((mb2 >> lane) & 1ull) ? __expf(e2 - m) : 0.f;
      float inv = 1.f / warp_sum(p1 + p2);
      att[i][lane] = p1 * inv;
      att[i][64 + lane] = p2 * inv;
    }
    __syncthreads();
    // PV via MFMA: wave w -> rows w*16.., ntiles 0..3 (cols 0..63), K=128
    f32x4 acc[4];
    #pragma unroll
    for (int nt = 0; nt < 4; ++nt) acc[nt] = (f32x4){0.f, 0.f, 0.f, 0.f};
    #pragma unroll
    for (int kt = 0; kt < 4; ++kt) {
      const float* ap = &att[w * 16 + r][kt * 32 + g * 8];
      float4 v0 = *(const float4*)ap;
      float4 v1 = *(const float4*)(ap + 4);
      bf16x8 ah, al;
      float av[8] = {v0.x, v0.y, v0.z, v0.w, v1.x, v1.y, v1.z, v1.w};
      #pragma unroll
      for (int e = 0; e < 8; ++e) {
        unsigned short h = f2bf(av[e]);
        ah[e] = (short)h;
        al[e] = (short)f2bf(av[e] - bf2f(h));
      }
      #pragma unroll
      for (int nt = 0; nt < 4; ++nt) {
        const bf16x8 bh = *(const bf16x8*)&Th[nt * 16 + r][kt * 32 + g * 8];
        const bf16x8 bl = *(const bf16x8*)&Tl[nt * 16 + r][kt * 32 + g * 8];
        acc[nt] = __builtin_amdgcn_mfma_f32_16x16x32_bf16(ah, bh, acc[nt], 0, 0, 0);
        acc[nt] = __builtin_amdgcn_mfma_f32_16x16x32_bf16(al, bh, acc[nt], 0, 0, 0);
        acc[nt] = __builtin_amdgcn_mfma_f32_16x16x32_bf16(ah, bl, acc[nt], 0, 0, 0);
      }
    }
    // ELU + in-place store
    #pragma unroll
    for (int nt = 0; nt < 4; ++nt) {
      const int cc = nt * 16 + r;
      if (cc < 60) {
        #pragma unroll
        for (int q = 0; q < 4; ++q) {
          float v = acc[nt][q];
          float o = v > 0.f ? v : __expf(v) - 1.f;
          whb[(size_t)(w * 16 + g * 4 + q) * 480 + hd * 60 + cc] = o;
        }
      }
    }
    __syncthreads();
  }
}

// ================= GAT layer 2 + elu + log_softmax + mean (rank-1) ==========
__global__ __launch_bounds__(512) void k_att2(
    const float* __restrict__ Wo, const int* __restrict__ adj,
    const float* __restrict__ aos, const float* __restrict__ aod,
    float* __restrict__ gat)
{
  __shared__ unsigned short Th[64][136], Tl[64][136];   // WoT chunk hi/lo
  __shared__ float att[128][132];
  __shared__ unsigned long long mA[128], mB[128];
  __shared__ float so[128], dof[128];
  __shared__ float aosl[304], aodl[304];
  __shared__ float colsum[304];
  __shared__ float srow[32];

  const int t = threadIdx.x, lane = t & 63, w = t >> 6;
  const int r = lane & 15, g = lane >> 4;
  const int b = blockIdx.x;
  const int* adjb = adj + (size_t)b * NN * NN;
  const float* wob = Wo + (size_t)b * NN * 300;

  for (int c = t; c < 304; c += 512) {
    aosl[c] = (c < 300) ? aos[c] : 0.f;
    aodl[c] = (c < 300) ? aod[c] : 0.f;
    colsum[c] = 0.f;
  }
  __syncthreads();
  // masks + s/d scores
  for (int rr2 = 0; rr2 < 16; ++rr2) {
    const int i = w * 16 + rr2;
    unsigned long long b0 = __ballot(adjb[i * NN + lane] > 0);
    unsigned long long b1 = __ballot(adjb[i * NN + 64 + lane] > 0);
    if (lane == 0) { mA[i] = b0; mB[i] = b1; }
    float s_ = 0.f, d_ = 0.f;
    for (int c = lane; c < 300; c += 64) {
      float wv = wob[(size_t)i * 300 + c];
      s_ += wv * aosl[c]; d_ += wv * aodl[c];
    }
    s_ = warp_sum(s_); d_ = warp_sum(d_);
    if (lane == 0) { so[i] = s_; dof[i] = d_; }
  }
  __syncthreads();
  // softmax rows
  for (int rr2 = 0; rr2 < 16; ++rr2) {
    const int i = w * 16 + rr2;
    const unsigned long long ma = mA[i], mb2 = mB[i];
    const float si = so[i];
    float e1 = -3e38f, e2 = -3e38f;
    if ((ma  >> lane) & 1ull) { float v = si + dof[lane];      e1 = v > 0.f ? v : LRA * v; }
    if ((mb2 >> lane) & 1ull) { float v = si + dof[64 + lane]; e2 = v > 0.f ? v : LRA * v; }
    float m = warp_max(fmaxf(e1, e2));
    float p1 = ((ma  >> lane) & 1ull) ? __expf(e1 - m) : 0.f;
    float p2 = ((mb2 >> lane) & 1ull) ? __expf(e2 - m) : 0.f;
    float inv = 1.f / warp_sum(p1 + p2);
    att[i][lane] = p1 * inv;
    att[i][64 + lane] = p2 * inv;
  }
  __syncthreads();

  float m4[4] = {-3e38f, -3e38f, -3e38f, -3e38f};
  float l4[4] = {0.f, 0.f, 0.f, 0.f};

  for (int ch = 0; ch < 5; ++ch) {
    // stage WoT chunk
    for (int jb = 0; jb < 16; ++jb) {
      const int j = jb * 8 + (t >> 6);
      const int c = t & 63;
      const int gc = ch * 64 + c;
      float v = (gc < 300) ? wob[(size_t)j * 300 + gc] : 0.f;
      unsigned short h = f2bf(v);
      Th[c][j] = h; Tl[c][j] = f2bf(v - bf2f(h));
    }
    __syncthreads();
    f32x4 pacc[4];
    #pragma unroll
    for (int nt = 0; nt < 4; ++nt) pacc[nt] = (f32x4){0.f, 0.f, 0.f, 0.f};
    #pragma unroll
    for (int kt = 0; kt < 4; ++kt) {
      const float* ap = &att[w * 16 + r][kt * 32 + g * 8];
      float4 v0 = *(const float4*)ap;
      float4 v1 = *(const float4*)(ap + 4);
      bf16x8 ah, al;
      float av[8] = {v0.x, v0.y, v0.z, v0.w, v1.x, v1.y, v1.z, v1.w};
      #pragma unroll
      for (int e = 0; e < 8; ++e) {
        unsigned short h = f2bf(av[e]);
        ah[e] = (short)h;
        al[e] = (short)f2bf(av[e] - bf2f(h));
      }
      #pragma unroll
      for (int nt = 0; nt < 4; ++nt) {
        const bf16x8 bh = *(const bf16x8*)&Th[nt * 16 + r][kt * 32 + g * 8];
        const bf16x8 bl = *(const bf16x8*)&Tl[nt * 16 + r][kt * 32 + g * 8];
        pacc[nt] = __builtin_amdgcn_mfma_f32_16x16x32_bf16(ah, bh, pacc[nt], 0, 0, 0);
        pacc[nt] = __builtin_amdgcn_mfma_f32_16x16x32_bf16(al, bh, pacc[nt], 0, 0, 0);
        pacc[nt] = __builtin_amdgcn_mfma_f32_16x16x32_bf16(ah, bl, pacc[nt], 0, 0, 0);
      }
    }
    // epilogue: ELU, online row max/lse, col sums
    float vmat[4][4], cs[4];
    #pragma unroll
    for (int nt = 0; nt < 4; ++nt) {
      const int cc = ch * 64 + nt * 16 + r;
      const bool cv = cc < 300;
      float s = 0.f;
      #pragma unroll
      for (int q = 0; q < 4; ++q) {
        float v = pacc[nt][q];
        v = v > 0.f ? v : __expf(v) - 1.f;
        vmat[nt][q] = cv ? v : -3e38f;
        s += cv ? v : 0.f;
      }
      cs[nt] = s;
    }
    #pragma unroll
    for (int q = 0; q < 4; ++q) {
      float mx = fmaxf(fmaxf(vmat[0][q], vmat[1][q]), fmaxf(vmat[2][q], vmat[3][q]));
      mx = fmaxf(mx, __shfl_xor(mx, 1));
      mx = fmaxf(mx, __shfl_xor(mx, 2));
      mx = fmaxf(mx, __shfl_xor(mx, 4));
      mx = fmaxf(mx, __shfl_xor(mx, 8));
      const float nm = fmaxf(m4[q], mx);
      float ps = __expf(vmat[0][q] - nm) + __expf(vmat[1][q] - nm)
               + __expf(vmat[2][q] - nm) + __expf(vmat[3][q] - nm);
      ps += __shfl_xor(ps, 1); ps += __shfl_xor(ps, 2);
      ps += __shfl_xor(ps, 4); ps += __shfl_xor(ps, 8);
      l4[q] = l4[q] * __expf(m4[q] - nm) + ps;
      m4[q] = nm;
    }
    #pragma unroll
    for (int nt = 0; nt < 4; ++nt) {
      float s = cs[nt];
      s += __shfl_xor(s, 16); s += __shfl_xor(s, 32);
      if (lane < 16) atomicAdd(&colsum[ch * 64 + nt * 16 + lane], s);
    }
    __syncthreads();
  }
  if (r == 0) {
    float sp = 0.f;
    #pragma unroll
    for (int q = 0; q < 4; ++q) sp += m4[q] + __logf(l4[q]);
    srow[w * 4 + g] = sp;
  }
  __syncthreads();
  float S = 0.f;
  #pragma unroll
  for (int k = 0; k < 32; ++k) S += srow[k];
  for (int c = t; c < 300; c += 512)
    gat[(size_t)b * 300 + c] = (colsum[c] - S) * (1.f / 128.f);
}

// ================= FPN branch =================
__global__ __launch_bounds__(256) void k_fpn(
    const float* __restrict__ fp, const float* __restrict__ w1, const float* __restrict__ b1,
    const float* __restrict__ w2, const float* __restrict__ b2, float* __restrict__ fpn)
{
  __shared__ float fpl[1492];
  __shared__ float f1[512];
  const int t = threadIdx.x, b = blockIdx.x;
  for (int k = t; k < 1489; k += 256) fpl[k] = fp[(size_t)b * 1489 + k];
  __syncthreads();
  {
    const int c0 = t, c1 = t + 256;
    float a00 = b1[c0], a01 = 0.f, a10 = b1[c1], a11 = 0.f;
    #pragma unroll 4
    for (int k = 0; k < 1488; k += 2) {
      const float x0 = fpl[k], x1 = fpl[k + 1];
      a00 += x0 * w1[(size_t)k * 512 + c0];
      a10 += x0 * w1[(size_t)k * 512 + c1];
      a01 += x1 * w1[(size_t)(k + 1) * 512 + c0];
      a11 += x1 * w1[(size_t)(k + 1) * 512 + c1];
    }
    { const float x0 = fpl[1488];
      a00 += x0 * w1[(size_t)1488 * 512 + c0];
      a10 += x0 * w1[(size_t)1488 * 512 + c1]; }
    f1[c0] = fmaxf(a00 + a01, 0.f);
    f1[c1] = fmaxf(a10 + a11, 0.f);
  }
  __syncthreads();
  for (int c = t; c < 300; c += 256) {
    float a0 = b2[c], a1 = 0.f;
    #pragma unroll 4
    for (int k = 0; k < 512; k += 2) {
      a0 += f1[k]     * w2[(size_t)k * 300 + c];
      a1 += f1[k + 1] * w2[(size_t)(k + 1) * 300 + c];
    }
    fpn[(size_t)b * 300 + c] = a0 + a1;
  }
}

// ================= fusion head =================
__global__ __launch_bounds__(256) void k_head(
    const float* __restrict__ gat, const float* __restrict__ fpn,
    const float* __restrict__ gw, const float* __restrict__ gb,
    const float* __restrict__ fw, const float* __restrict__ fb,
    const float* __restrict__ w1, const float* __restrict__ b1,
    const float* __restrict__ w2, const float* __restrict__ b2,
    float* __restrict__ out)
{
  __shared__ float grl[300], frl[300];
  __shared__ float zl[600];
  __shared__ float z1l[304];
  __shared__ float red[4];
  const int t = threadIdx.x, b = blockIdx.x, lane = t & 63, w = t >> 6;
  for (int k = t; k < 300; k += 256) {
    grl[k] = gat[(size_t)b * 300 + k];
    frl[k] = fpn[(size_t)b * 300 + k];
  }
  __syncthreads();
  for (int c = t; c < 300; c += 256) {
    float ag0 = gb[c], ag1 = 0.f, af0 = fb[c], af1 = 0.f;
    #pragma unroll 2
    for (int k = 0; k < 300; k += 2) {
      ag0 += grl[k]     * gw[(size_t)k * 300 + c];
      ag1 += grl[k + 1] * gw[(size_t)(k + 1) * 300 + c];
      af0 += frl[k]     * fw[(size_t)k * 300 + c];
      af1 += frl[k + 1] * fw[(size_t)(k + 1) * 300 + c];
    }
    zl[c] = fmaxf(ag0 + ag1, 0.f);
    zl[300 + c] = fmaxf(af0 + af1, 0.f);
  }
  __syncthreads();
  for (int c = t; c < 300; c += 256) {
    float a0 = b1[c], a1 = 0.f;
    #pragma unroll 2
    for (int k = 0; k < 600; k += 2) {
      a0 += zl[k]     * w1[(size_t)k * 300 + c];
      a1 += zl[k + 1] * w1[(size_t)(k + 1) * 300 + c];
    }
    z1l[c] = fmaxf(a0 + a1, 0.f);
  }
  __syncthreads();
  float p = 0.f;
  for (int k = t; k < 300; k += 256) p += z1l[k] * w2[k];
  p = warp_sum(p);
  if (lane == 0) red[w] = p;
  __syncthreads();
  if (t == 0) {
    float z = red[0] + red[1] + red[2] + red[3] + b2[0];
    out[b] = 1.f / (1.f + __expf(-z));
  }
}

extern "C" void kernel_launch(void* const* d_in, const int* in_sizes, int n_in,
                              void* d_out, int out_size, void* d_ws, size_t ws_size,
                              hipStream_t stream)
{
  const float* x    = (const float*)d_in[0];
  const int*   adj  = (const int*)d_in[1];
  const float* fp   = (const float*)d_in[2];
  const float* Whw  = (const float*)d_in[3];
  const float* asrc = (const float*)d_in[4];
  const float* adst = (const float*)d_in[5];
  const float* Wout = (const float*)d_in[6];
  const float* aos  = (const float*)d_in[7];
  const float* aod  = (const float*)d_in[8];
  const float* fc1w = (const float*)d_in[9];
  const float* fc1b = (const float*)d_in[10];
  const float* fc2w = (const float*)d_in[11];
  const float* fc2b = (const float*)d_in[12];
  const float* fcgw = (const float*)d_in[13];
  const float* fcgb = (const float*)d_in[14];
  const float* fcfw = (const float*)d_in[15];
  const float* fcfb = (const float*)d_in[16];
  const float* f1w  = (const float*)d_in[17];
  const float* f1b  = (const float*)d_in[18];
  const float* f2w  = (const float*)d_in[19];
  const float* f2b  = (const float*)d_in[20];
  float* out = (float*)d_out;

  const size_t nH  = (size_t)512 * 128 * 480;   // 31,457,280
  const size_t nWo = (size_t)512 * 128 * 300;   // 19,660,800
  const size_t nG  = (size_t)512 * 300;

  char* wsb = (char*)d_ws;
  float* Wh   = (float*)wsb;                       // also becomes h (in-place)
  float* Wo   = (float*)(wsb + nH * 4);
  float* gatp = (float*)(wsb + (nH + nWo) * 4);
  float* fpnp = gatp + nG;

  // GEMM1: Wh = x @ Bcat   (65536 x 133 x 480)
  k_gemm<96, 1, false><<<dim3(512, 5), 256, 0, stream>>>(x, Whw, Wh, 65536, 133, 480);
  // GAT1 attention + ELU, h written in-place over Wh
  k_att1<<<512, 512, 0, stream>>>(Wh, adj, asrc, adst);
  // GEMM2: Wo = h @ W_out  (65536 x 480 x 300)
  k_gemm<160, 0, true><<<dim3(512, 2), 256, 0, stream>>>(Wh, Wout, Wo, 65536, 480, 300);
  // GAT2 attention + elu + log_softmax + mean
  k_att2<<<512, 512, 0, stream>>>(Wo, adj, aos, aod, gatp);
  // FPN + head
  k_fpn<<<512, 256, 0, stream>>>(fp, fc1w, fc1b, fc2w, fc2b, fpnp);
  k_head<<<512, 256, 0, stream>>>(gatp, fpnp, fcgw, fcgb, fcfw, fcfb,
                                  f1w, f1b, f2w, f2b, out);
}